// Round 1
// baseline (98.188 us; speedup 1.0000x reference)
//
#include <hip/hip_runtime.h>
#include <hip/hip_bf16.h>
#include <stdint.h>

// LSTMCell: B=64, T=256, D=32, N=64.
// gate[b,d,m] = sum_n h[b,d,n]*W[d,n,m] + x[b,t,d]*U[d,m] + bias[d,m]
//
// R12: ONE BLOCK PER CU. Topology: 256 blocks = 32d x 8 batch-tiles of 8,
// 4 waves/block -> 1024 waves = 1 block/CU, 1 wave/SIMD. The R10/R11 wall
// (754 cy/step ~= 2x the ~380 cy per-SIMD issue; co-resident blocks from
// different barriers stalling together, immune to stagger/setprio) is
// removed structurally: no co-resident block exists.
//
// Cost: 2 elements/lane. 8 batches sit in MFMA rows {0,1,4,5,8,9,12,13}
// (row = 4*(bb>>1) + (bb&1)), so acc regs 0,1 are live (C row = 4*(lane>>4)
// + reg -> batch 2*(lane>>4)+reg); regs 2,3 accumulate finite junk from the
// duplicate-broadcast A rows and are never read. MFMA count halves at 2x
// row density; activation VALU doubles per lane (~130 cy issue, still
// under the ~350-450 cy chain).
//
// h exchange: hbuf[2][8][72] bf16. 72-elem (144 B) row stride rotates each
// row's bank group by 4 banks (36 words % 32 = 4): ds_read_b128 lands at
// the 4-way conflict floor (32 distinct 16B addrs over 32 banks is >=4-way
// by counting), writes are conflict-free. Junk A lanes (li&3 in {2,3})
// quad-share their leader pair's address -> broadcast, free.
//
// MFMA k-placement: logical k = f*32 + 8*(lane>>4) + j in slot (f,g,j) for
// BOTH A and B -> exact dot product under any HW slot->k bijection.
// C/D layout (HW-verified): col=lane&15, row=4*(lane>>4)+reg.
//
// Barrier: lgkmcnt-only drain + raw s_barrier (NOT __syncthreads: vmcnt(0)
// would pull the fire-and-forget global h stores into the critical path).
// Double-buffered hbuf -> one barrier/step (write next buffer, read current).
// Stagger sleep + setprio removed: nothing to de-phase / arbitrate against.

typedef __attribute__((ext_vector_type(8))) __bf16 bf16x8;
typedef __attribute__((ext_vector_type(4))) float f32x4;

union FragU { uint4 u; bf16x8 v; };

__device__ __forceinline__ float fast_sigmoid(float x) {
    float e = __builtin_amdgcn_exp2f(-1.4426950408889634f * x);
    return __builtin_amdgcn_rcpf(1.0f + e);
}
__device__ __forceinline__ float fast_tanh(float x) {
    float e = __builtin_amdgcn_exp2f(2.8853900817779268f * x);  // exp(2x)
    return 1.0f - 2.0f * __builtin_amdgcn_rcpf(1.0f + e);
}

__global__ __launch_bounds__(256, 1) void lstm_kernel(
    const float* __restrict__ x,
    const float* __restrict__ Wj, const float* __restrict__ Wi,
    const float* __restrict__ Wf, const float* __restrict__ Wo,
    const float* __restrict__ Uj, const float* __restrict__ Ui,
    const float* __restrict__ Uf, const float* __restrict__ Uo,
    const float* __restrict__ bj, const float* __restrict__ bi,
    const float* __restrict__ bf, const float* __restrict__ bo,
    float* __restrict__ out)
{
    constexpr int T = 256, D = 32, N = 64, B = 64;
    const int bid   = blockIdx.x;     // 0..255
    const int d     = bid >> 3;       // 0..31
    const int btile = bid & 7;        // 0..7 (8 batches each)
    const int tid   = threadIdx.x;
    const int w     = tid >> 6;       // wave 0..3
    const int lane  = tid & 63;
    const int q     = lane >> 4;      // lane group 0..3
    const int li    = lane & 15;
    const int mcol  = w * 16 + li;    // output feature owned by this lane

    // h exchange: [buf][batch row 0..7][72] bf16, 144 B row stride (bank
    // rotation by 4/row). Cols 64..71 are pad.
    __shared__ __align__(16) __bf16 hbuf[2][8][72];
    __shared__ __align__(16) float xs[8][256];   // x[batch][t] for (d,btile)

    for (int idx = tid; idx < 2 * 8 * 72; idx += 256)
        (&hbuf[0][0][0])[idx] = (__bf16)0.0f;          // h0 = 0
    for (int idx = tid; idx < 8 * 256; idx += 256) {
        int bl = idx >> 8, t = idx & 255;
        xs[bl][t] = x[((size_t)(btile * 8 + bl) * T + t) * D + d];
    }

    // Persistent per-lane operands: W B-fragments (32 VGPR), U, bias.
    const float* Wg[4] = { Wj, Wi, Wf, Wo };
    const float* Ug[4] = { Uj, Ui, Uf, Uo };
    const float* Bg[4] = { bj, bi, bf, bo };
    FragU wfrag[4][2];
    float uv[4], bv[4];
    #pragma unroll
    for (int G = 0; G < 4; ++G) {
        uv[G] = Ug[G][d * N + mcol];
        bv[G] = Bg[G][d * N + mcol];
        const float* base = Wg[G] + (size_t)d * N * N + mcol;
        #pragma unroll
        for (int f = 0; f < 2; ++f) {
            const int k0 = f * 32 + q * 8;
            bf16x8 tmp;
            #pragma unroll
            for (int j = 0; j < 8; ++j)
                tmp[j] = (__bf16)base[(size_t)(k0 + j) * N];  // W[d][k][m]
            wfrag[G][f].v = tmp;
        }
    }

    f32x4 acc[4];
    #pragma unroll
    for (int G = 0; G < 4; ++G)
        acc[G] = f32x4{ bv[G], bv[G], bv[G], bv[G] };

    // Writer: lane owns batches bb0=2q (acc reg 0) and bb1=2q+1 (reg 1)
    // at col mcol.
    const int bb0 = 2 * q, bb1 = 2 * q + 1;
    __bf16* hw0a = &hbuf[0][bb0][mcol];
    __bf16* hw0b = &hbuf[0][bb1][mcol];
    __bf16* hw1a = &hbuf[1][bb0][mcol];
    __bf16* hw1b = &hbuf[1][bb1][mcol];

    // Reader: A row (l&15) carries batch rr; junk rows (li&3 in {2,3})
    // duplicate their pair leader's address (broadcast, free).
    const int rr = 2 * (li >> 2) + (li & 1);
    const uint4* ra00 = (const uint4*)&hbuf[0][rr][q * 8];        // khalf 0
    const uint4* ra01 = (const uint4*)&hbuf[1][rr][q * 8];
    const uint4* ra10 = (const uint4*)&hbuf[0][rr][32 + q * 8];   // khalf 1
    const uint4* ra11 = (const uint4*)&hbuf[1][rr][32 + q * 8];

    __syncthreads();

    float c0a = 0.f, h0a = 0.f, c0b = 0.f, h0b = 0.f;
    const int gb0 = btile * 8 + bb0;  // global batches
    const int gb1 = gb0 + 1;
    uint32_t oidx0 = (uint32_t)gb0 * (T * D * N) + (uint32_t)(d * N + mcol);
    uint32_t oidx1 = (uint32_t)gb1 * (T * D * N) + (uint32_t)(d * N + mcol);

    #pragma unroll 1
    for (int t = 0; t < T; t += 8) {
        const float4 xa0 = *(const float4*)&xs[bb0][t];
        const float4 xb0 = *(const float4*)&xs[bb0][t + 4];
        const float4 xa1 = *(const float4*)&xs[bb1][t];
        const float4 xb1 = *(const float4*)&xs[bb1][t + 4];
        #pragma unroll
        for (int uu = 0; uu < 8; ++uu) {
            const int rb = uu & 1;             // read buffer = tt&1
            FragU a0, a1;
            a0.u = *(rb ? ra01 : ra00);
            a1.u = *(rb ? ra11 : ra10);
            const float xv0 = (uu < 4) ? xa0[uu] : xb0[uu - 4];
            const float xv1 = (uu < 4) ? xa1[uu] : xb1[uu - 4];
            #pragma unroll
            for (int G = 0; G < 4; ++G) {
                acc[G][0] = __builtin_fmaf(xv0, uv[G], bv[G]);
                acc[G][1] = __builtin_fmaf(xv1, uv[G], bv[G]);
            }
            #pragma unroll
            for (int G = 0; G < 4; ++G) {
                acc[G] = __builtin_amdgcn_mfma_f32_16x16x32_bf16(a0.v, wfrag[G][0].v, acc[G], 0, 0, 0);
                acc[G] = __builtin_amdgcn_mfma_f32_16x16x32_bf16(a1.v, wfrag[G][1].v, acc[G], 0, 0, 0);
            }
            const float jja = fast_tanh   (acc[0][0]);
            const float iia = fast_sigmoid(acc[1][0]);
            const float ffa = fast_sigmoid(acc[2][0]);
            const float ooa = fast_sigmoid(acc[3][0]);
            c0a = __builtin_fmaf(c0a, ffa, iia * jja);
            h0a = ooa * fast_tanh(c0a);
            const float jjb = fast_tanh   (acc[0][1]);
            const float iib = fast_sigmoid(acc[1][1]);
            const float ffb = fast_sigmoid(acc[2][1]);
            const float oob = fast_sigmoid(acc[3][1]);
            c0b = __builtin_fmaf(c0b, ffb, iib * jjb);
            h0b = oob * fast_tanh(c0b);
            if (rb) { *hw0a = (__bf16)h0a; *hw0b = (__bf16)h0b; }  // write NEXT buffer
            else    { *hw1a = (__bf16)h0a; *hw1b = (__bf16)h0b; }
            out[oidx0] = h0a;                  // fire-and-forget (drain shadow)
            out[oidx1] = h0b;
            oidx0 += D * N;
            oidx1 += D * N;
            asm volatile("s_waitcnt lgkmcnt(0)" ::: "memory");
            __builtin_amdgcn_s_barrier();
        }
    }

    // h_T (B,D,N) then c_T (B,D,N), appended after outputs.
    const size_t baseH = (size_t)B * T * D * N;
    const size_t baseC = baseH + (size_t)B * D * N;
    const size_t i0 = ((size_t)gb0 * D + d) * N + mcol;
    const size_t i1 = ((size_t)gb1 * D + d) * N + mcol;
    out[baseH + i0] = h0a;
    out[baseC + i0] = c0a;
    out[baseH + i1] = h0b;
    out[baseC + i1] = c0b;
}

extern "C" void kernel_launch(void* const* d_in, const int* in_sizes, int n_in,
                              void* d_out, int out_size, void* d_ws, size_t ws_size,
                              hipStream_t stream) {
    lstm_kernel<<<dim3(256), dim3(256), 0, stream>>>(
        (const float*)d_in[0],
        (const float*)d_in[1], (const float*)d_in[2],
        (const float*)d_in[3], (const float*)d_in[4],
        (const float*)d_in[5], (const float*)d_in[6],
        (const float*)d_in[7], (const float*)d_in[8],
        (const float*)d_in[9], (const float*)d_in[10],
        (const float*)d_in[11], (const float*)d_in[12],
        (float*)d_out);
}

// Round 2
// 86.274 us; speedup vs baseline: 1.1381x; 1.1381x over previous
//
#include <hip/hip_runtime.h>
#include <hip/hip_bf16.h>
#include <stdint.h>

// LSTMCell: B=64, T=256, D=32, N=64.
// gate[b,d,m] = sum_n h[b,d,n]*W[d,n,m] + x[b,t,d]*U[d,m] + bias[d,m]
//
// Topology (R4/R9, proven 80.2us): 512 blocks = 32d x 16 batch-tiles of 4,
// 4 waves/block, 2048 waves = 2 blocks/CU, 2 waves/SIMD from DIFFERENT
// blocks. Batches at MFMA rows {0,4,8,12}: each lane owns 1 element
// (batch g, col mcol) in acc reg 0; junk A rows (quad-broadcast) feed only
// never-read C regs 1..3.
//
// R13 = R11 topology + CHAIN SHORTENING. R12 (1 block/CU, 2-elem ILP)
// measured 1088 cy/step vs R11's 754: the ~1000cy serial chain is NOT
// fillable by in-step software ILP; only a co-resident block overlaps it
// across steps. So: keep w=2, cut L.
//   (a) ZERO-C MFMA: both k-half MFMAs take a loop-invariant zero C
//       operand -> no VALU-seed->MFMA C-in hazard, and the 8 MFMAs/step
//       are all mutually independent (one MFMA latency, not a 2-chain).
//   (b) x*U + b moved OFF the pre-MFMA path: computed during the MFMA
//       shadow, added at readout: gate = accA[0] + accB[0] + xub.
// Cost: +16 VGPR (two acc sets), +4 VALU/step. Budget fine at 2 waves/SIMD.
//
// MFMA k-placement: logical k=8g+j in slot (g,j) for BOTH A and B -> exact
// dot product under any HW slot->k bijection. C/D layout (HW-verified):
// col=lane&15, row=4*(lane>>4)+reg.
//
// Anti-phase stagger (pairing-robust hash) + setprio kept from the 80.2us
// kernel: offset one block of every co-resident pair by ~384cy once;
// setprio stabilizes the anti-phase.
//
// Barrier: lgkmcnt-only drain + raw s_barrier (NOT __syncthreads: vmcnt(0)
// would pull the fire-and-forget global h stores into the critical path).

typedef __attribute__((ext_vector_type(8))) __bf16 bf16x8;
typedef __attribute__((ext_vector_type(4))) float f32x4;

union FragU { uint4 u; bf16x8 v; };

__device__ __forceinline__ float fast_sigmoid(float x) {
    float e = __builtin_amdgcn_exp2f(-1.4426950408889634f * x);
    return __builtin_amdgcn_rcpf(1.0f + e);
}
__device__ __forceinline__ float fast_tanh(float x) {
    float e = __builtin_amdgcn_exp2f(2.8853900817779268f * x);  // exp(2x)
    return 1.0f - 2.0f * __builtin_amdgcn_rcpf(1.0f + e);
}

__global__ __launch_bounds__(256, 2) void lstm_kernel(
    const float* __restrict__ x,
    const float* __restrict__ Wj, const float* __restrict__ Wi,
    const float* __restrict__ Wf, const float* __restrict__ Wo,
    const float* __restrict__ Uj, const float* __restrict__ Ui,
    const float* __restrict__ Uf, const float* __restrict__ Uo,
    const float* __restrict__ bj, const float* __restrict__ bi,
    const float* __restrict__ bf, const float* __restrict__ bo,
    float* __restrict__ out)
{
    constexpr int T = 256, D = 32, N = 64, B = 64;
    const int bid   = blockIdx.x;     // 0..511
    const int d     = bid >> 4;       // 0..31
    const int btile = bid & 15;      // 0..15 (4 batches each)
    const int tid   = threadIdx.x;
    const int w     = tid >> 6;       // wave 0..3
    const int lane  = tid & 63;
    const int g     = lane >> 4;      // lane group 0..3
    const int li    = lane & 15;
    const int mcol  = w * 16 + li;    // output feature owned by this lane

    // Compact h exchange: [buf][batch r][64 cols, 16B-chunk-swizzled
    // p = (chunk + 2r) & 7].
    __shared__ __align__(16) __bf16 hbuf[2][4][64];
    __shared__ float xs[4][256];      // x[batch][t] for this (d, btile)

    for (int idx = tid; idx < 2 * 4 * 64; idx += 256)
        (&hbuf[0][0][0])[idx] = (__bf16)0.0f;          // h0 = 0
    for (int idx = tid; idx < 4 * 256; idx += 256) {
        int bl = idx >> 8, t = idx & 255;
        xs[bl][t] = x[((size_t)(btile * 4 + bl) * T + t) * D + d];
    }

    // Persistent per-lane operands: W B-fragments (32 VGPR), U, bias.
    const float* Wg[4] = { Wj, Wi, Wf, Wo };
    const float* Ug[4] = { Uj, Ui, Uf, Uo };
    const float* Bg[4] = { bj, bi, bf, bo };
    FragU wfrag[4][2];
    float uv[4], bv[4];
    #pragma unroll
    for (int G = 0; G < 4; ++G) {
        uv[G] = Ug[G][d * N + mcol];
        bv[G] = Bg[G][d * N + mcol];
        const float* base = Wg[G] + (size_t)d * N * N + mcol;
        #pragma unroll
        for (int f = 0; f < 2; ++f) {
            const int k0 = f * 32 + g * 8;
            bf16x8 tmp;
            #pragma unroll
            for (int j = 0; j < 8; ++j)
                tmp[j] = (__bf16)base[(size_t)(k0 + j) * N];  // W[d][k][m]
            wfrag[G][f].v = tmp;
        }
    }

    // Loop-invariant zero C operand (no VALU->MFMA hazard, no per-step reset).
    f32x4 zeroacc = f32x4{ 0.f, 0.f, 0.f, 0.f };

    // Writer: lane owns (batch g, col mcol) -> row g, swizzled chunk.
    const int cm = mcol >> 3;
    const int woff = (((cm + 2 * g) & 7) << 3) | (mcol & 7);
    __bf16* hw0 = &hbuf[0][g][0] + woff;
    __bf16* hw1 = &hbuf[1][g][0] + woff;

    // Reader (ALL lanes; quads broadcast their leader's address).
    const int rr = li >> 2;                   // A row quad -> batch rr
    const int p0 = (g + 2 * rr) & 7;          // logical chunk g
    const int p1 = (g + 4 + 2 * rr) & 7;      // logical chunk g+4
    const uint4* ra00 = (const uint4*)&hbuf[0][rr][p0 << 3];
    const uint4* ra01 = (const uint4*)&hbuf[1][rr][p0 << 3];
    const uint4* ra10 = (const uint4*)&hbuf[0][rr][p1 << 3];
    const uint4* ra11 = (const uint4*)&hbuf[1][rr][p1 << 3];

    __syncthreads();

    // ANTI-PHASE STAGGER, pairing-robust hash: offset one block of every
    // co-resident pair by ~384 cy (~half a step), once.
    if (((bid >> 3) ^ (bid >> 8)) & 1)
        asm volatile("s_sleep 6" ::: "memory");

    float c0 = 0.f, h0 = 0.f;
    const int gb = btile * 4 + g;     // global batch
    uint32_t oidx = (uint32_t)gb * (T * D * N) + (uint32_t)(d * N + mcol);

    #pragma unroll 1
    for (int t = 0; t < T; t += 8) {
        const float4 xa = *(const float4*)&xs[g][t];
        const float4 xb = *(const float4*)&xs[g][t + 4];
        #pragma unroll
        for (int uu = 0; uu < 8; ++uu) {
            // CHAIN HEAD at high priority: preempts the co-resident block's
            // tail -> anti-phase is the stable fixed point.
            __builtin_amdgcn_s_setprio(1);
            const int rb = uu & 1;             // read buffer = tt&1
            FragU a0, a1;
            a0.u = *(rb ? ra01 : ra00);
            a1.u = *(rb ? ra11 : ra10);
            const float xv = (uu < 4) ? xa[uu] : xb[uu - 4];
            // x*U + b in the MFMA shadow (off the dependent path).
            float xub[4];
            #pragma unroll
            for (int G = 0; G < 4; ++G)
                xub[G] = __builtin_fmaf(xv, uv[G], bv[G]);
            // 8 mutually independent MFMAs: both k-halves into separate
            // zero-seeded accumulators (no 2-deep chain, no C-in hazard).
            f32x4 accA[4], accB[4];
            #pragma unroll
            for (int G = 0; G < 4; ++G)
                accA[G] = __builtin_amdgcn_mfma_f32_16x16x32_bf16(a0.v, wfrag[G][0].v, zeroacc, 0, 0, 0);
            #pragma unroll
            for (int G = 0; G < 4; ++G)
                accB[G] = __builtin_amdgcn_mfma_f32_16x16x32_bf16(a1.v, wfrag[G][1].v, zeroacc, 0, 0, 0);
            const float gj = accA[0][0] + accB[0][0] + xub[0];
            const float gi = accA[1][0] + accB[1][0] + xub[1];
            const float gf = accA[2][0] + accB[2][0] + xub[2];
            const float go = accA[3][0] + accB[3][0] + xub[3];
            const float jj = fast_tanh   (gj);
            const float ii = fast_sigmoid(gi);
            const float ff = fast_sigmoid(gf);
            const float oo = fast_sigmoid(go);
            c0 = __builtin_fmaf(c0, ff, ii * jj);
            h0 = oo * fast_tanh(c0);
            // TAIL at low priority: yields issue slots to the other block.
            __builtin_amdgcn_s_setprio(0);
            *(rb ? hw0 : hw1) = (__bf16)h0;    // write NEXT buffer
            out[oidx] = h0;                    // fire-and-forget (drain shadow)
            oidx += D * N;
            asm volatile("s_waitcnt lgkmcnt(0)" ::: "memory");
            __builtin_amdgcn_s_barrier();
        }
    }

    // h_T (B,D,N) then c_T (B,D,N), appended after outputs.
    const size_t baseH = (size_t)B * T * D * N;
    const size_t baseC = baseH + (size_t)B * D * N;
    const size_t i0 = ((size_t)gb * D + d) * N + mcol;
    out[baseH + i0] = h0;
    out[baseC + i0] = c0;
}

extern "C" void kernel_launch(void* const* d_in, const int* in_sizes, int n_in,
                              void* d_out, int out_size, void* d_ws, size_t ws_size,
                              hipStream_t stream) {
    lstm_kernel<<<dim3(512), dim3(256), 0, stream>>>(
        (const float*)d_in[0],
        (const float*)d_in[1], (const float*)d_in[2],
        (const float*)d_in[3], (const float*)d_in[4],
        (const float*)d_in[5], (const float*)d_in[6],
        (const float*)d_in[7], (const float*)d_in[8],
        (const float*)d_in[9], (const float*)d_in[10],
        (const float*)d_in[11], (const float*)d_in[12],
        (float*)d_out);
}

// Round 3
// 80.716 us; speedup vs baseline: 1.2165x; 1.0689x over previous
//
#include <hip/hip_runtime.h>
#include <hip/hip_bf16.h>
#include <stdint.h>

// LSTMCell: B=64, T=256, D=32, N=64.
// gate[b,d,m] = sum_n h[b,d,n]*W[d,n,m] + x[b,t,d]*U[d,m] + bias[d,m]
//
// Topology (R4/R9, proven 80.2-80.5us): 512 blocks = 32d x 16 batch-tiles
// of 4, 4 waves/block, 2048 waves = 2 blocks/CU, 2 waves/SIMD from
// DIFFERENT blocks. Batches at MFMA rows {0,4,8,12}: each lane owns 1
// element (batch g, col mcol) in acc reg 0; junk A rows (quad-broadcast)
// feed only never-read C regs 1..3.
//
// R14 = R11 + PHYSICAL pair stagger. Wall accounting (fits exactly):
//   MFMA pipe 2x155=310 + VALU/trans 2x~220=440 ~= 754 cy/step measured
// -> the two waves per SIMD are phase-locked IN-PHASE (pipes additive).
// Anti-phase would overlap MFMA under VALU -> ~550-620 cy/step. R10/R11
// staggers hashed blockIdx to guess SIMD pairing; a wrong guess sleeps
// both or neither member of every real pair = no-op (matches their null
// results). Fix: read the wave's PHYSICAL slot via s_getreg HW_ID
// (bits[3:0]=WAVE_ID, slot on the SIMD). Co-resident blocks occupy
// different slots on the shared SIMD, so wave0 slot parity is a correct
// pair discriminator. Broadcast wave0's parity via LDS; odd-slot block
// sleeps ~384cy (~half step) once. setprio (R9, +2%) kept: stabilizes
// the anti-phase once created.
//
// R12 lesson: 1 block/CU with 2-elem in-step ILP = 921 cy/step -> the
// chain is only hideable ACROSS blocks, not within a step. R13 lesson:
// zero-C split MFMAs lengthen the readout chain (+55 cy/step); chained-C
// MFMA with VALU seed is the faster form.
//
// MFMA k-placement: logical k=8g+j in slot (g,j) for BOTH A and B -> exact
// dot product under any HW slot->k bijection. C/D layout (HW-verified):
// col=lane&15, row=4*(lane>>4)+reg.
//
// Barrier: lgkmcnt-only drain + raw s_barrier (NOT __syncthreads: vmcnt(0)
// would pull the fire-and-forget global h stores into the critical path).

typedef __attribute__((ext_vector_type(8))) __bf16 bf16x8;
typedef __attribute__((ext_vector_type(4))) float f32x4;

union FragU { uint4 u; bf16x8 v; };

__device__ __forceinline__ float fast_sigmoid(float x) {
    float e = __builtin_amdgcn_exp2f(-1.4426950408889634f * x);
    return __builtin_amdgcn_rcpf(1.0f + e);
}
__device__ __forceinline__ float fast_tanh(float x) {
    float e = __builtin_amdgcn_exp2f(2.8853900817779268f * x);  // exp(2x)
    return 1.0f - 2.0f * __builtin_amdgcn_rcpf(1.0f + e);
}

__global__ __launch_bounds__(256, 2) void lstm_kernel(
    const float* __restrict__ x,
    const float* __restrict__ Wj, const float* __restrict__ Wi,
    const float* __restrict__ Wf, const float* __restrict__ Wo,
    const float* __restrict__ Uj, const float* __restrict__ Ui,
    const float* __restrict__ Uf, const float* __restrict__ Uo,
    const float* __restrict__ bj, const float* __restrict__ bi,
    const float* __restrict__ bf, const float* __restrict__ bo,
    float* __restrict__ out)
{
    constexpr int T = 256, D = 32, N = 64, B = 64;
    const int bid   = blockIdx.x;     // 0..511
    const int d     = bid >> 4;       // 0..31
    const int btile = bid & 15;       // 0..15 (4 batches each)
    const int tid   = threadIdx.x;
    const int w     = tid >> 6;       // wave 0..3
    const int lane  = tid & 63;
    const int g     = lane >> 4;      // lane group 0..3
    const int li    = lane & 15;
    const int mcol  = w * 16 + li;    // output feature owned by this lane

    // Compact h exchange: [buf][batch r][64 cols, 16B-chunk-swizzled
    // p = (chunk + 2r) & 7].
    __shared__ __align__(16) __bf16 hbuf[2][4][64];
    __shared__ float xs[4][256];      // x[batch][t] for this (d, btile)
    __shared__ int stag;              // block stagger flag (wave0 slot parity)

    for (int idx = tid; idx < 2 * 4 * 64; idx += 256)
        (&hbuf[0][0][0])[idx] = (__bf16)0.0f;          // h0 = 0
    for (int idx = tid; idx < 4 * 256; idx += 256) {
        int bl = idx >> 8, t = idx & 255;
        xs[bl][t] = x[((size_t)(btile * 4 + bl) * T + t) * D + d];
    }

    // PHYSICAL pairing probe: HW_REG_HW_ID (id=4), offset 0, size 4 ->
    // WAVE_ID = this wave's slot on its SIMD. Encoding: id | off<<6 |
    // (size-1)<<11. Co-resident blocks hold different slots on the shared
    // SIMD -> wave0 slot parity discriminates the pair.
    const uint32_t slot = __builtin_amdgcn_s_getreg(4 | (0 << 6) | (3 << 11));
    if (tid == 0) stag = (int)(slot & 1);

    // Persistent per-lane operands: W B-fragments (32 VGPR), U, bias.
    const float* Wg[4] = { Wj, Wi, Wf, Wo };
    const float* Ug[4] = { Uj, Ui, Uf, Uo };
    const float* Bg[4] = { bj, bi, bf, bo };
    FragU wfrag[4][2];
    float uv[4], bv[4];
    #pragma unroll
    for (int G = 0; G < 4; ++G) {
        uv[G] = Ug[G][d * N + mcol];
        bv[G] = Bg[G][d * N + mcol];
        const float* base = Wg[G] + (size_t)d * N * N + mcol;
        #pragma unroll
        for (int f = 0; f < 2; ++f) {
            const int k0 = f * 32 + g * 8;
            bf16x8 tmp;
            #pragma unroll
            for (int j = 0; j < 8; ++j)
                tmp[j] = (__bf16)base[(size_t)(k0 + j) * N];  // W[d][k][m]
            wfrag[G][f].v = tmp;
        }
    }

    f32x4 acc[4];
    #pragma unroll
    for (int G = 0; G < 4; ++G)
        acc[G] = f32x4{ bv[G], bv[G], bv[G], bv[G] };

    // Writer: lane owns (batch g, col mcol) -> row g, swizzled chunk.
    const int cm = mcol >> 3;
    const int woff = (((cm + 2 * g) & 7) << 3) | (mcol & 7);
    __bf16* hw0 = &hbuf[0][g][0] + woff;
    __bf16* hw1 = &hbuf[1][g][0] + woff;

    // Reader (ALL lanes; quads broadcast their leader's address).
    const int rr = li >> 2;                   // A row quad -> batch rr
    const int p0 = (g + 2 * rr) & 7;          // logical chunk g
    const int p1 = (g + 4 + 2 * rr) & 7;      // logical chunk g+4
    const uint4* ra00 = (const uint4*)&hbuf[0][rr][p0 << 3];
    const uint4* ra01 = (const uint4*)&hbuf[1][rr][p0 << 3];
    const uint4* ra10 = (const uint4*)&hbuf[0][rr][p1 << 3];
    const uint4* ra11 = (const uint4*)&hbuf[1][rr][p1 << 3];

    __syncthreads();

    // ANTI-PHASE STAGGER on PHYSICAL slot parity: the odd-slot block of
    // every co-resident pair offsets by ~384 cy (~half a step), once.
    if (stag)
        asm volatile("s_sleep 6" ::: "memory");

    float c0 = 0.f, h0 = 0.f;
    const int gb = btile * 4 + g;     // global batch
    uint32_t oidx = (uint32_t)gb * (T * D * N) + (uint32_t)(d * N + mcol);

    #pragma unroll 1
    for (int t = 0; t < T; t += 8) {
        const float4 xa = *(const float4*)&xs[g][t];
        const float4 xb = *(const float4*)&xs[g][t + 4];
        #pragma unroll
        for (int uu = 0; uu < 8; ++uu) {
            // CHAIN HEAD at high priority: preempts the co-resident block's
            // tail -> anti-phase is the stable fixed point.
            __builtin_amdgcn_s_setprio(1);
            const int rb = uu & 1;             // read buffer = tt&1
            FragU a0, a1;
            a0.u = *(rb ? ra01 : ra00);
            a1.u = *(rb ? ra11 : ra10);
            const float xv = (uu < 4) ? xa[uu] : xb[uu - 4];
            #pragma unroll
            for (int G = 0; G < 4; ++G)
                acc[G][0] = __builtin_fmaf(xv, uv[G], bv[G]);
            #pragma unroll
            for (int G = 0; G < 4; ++G) {
                acc[G] = __builtin_amdgcn_mfma_f32_16x16x32_bf16(a0.v, wfrag[G][0].v, acc[G], 0, 0, 0);
                acc[G] = __builtin_amdgcn_mfma_f32_16x16x32_bf16(a1.v, wfrag[G][1].v, acc[G], 0, 0, 0);
            }
            const float jj = fast_tanh   (acc[0][0]);
            const float ii = fast_sigmoid(acc[1][0]);
            const float ff = fast_sigmoid(acc[2][0]);
            const float oo = fast_sigmoid(acc[3][0]);
            c0 = __builtin_fmaf(c0, ff, ii * jj);
            h0 = oo * fast_tanh(c0);
            // TAIL at low priority: yields issue slots to the other block.
            __builtin_amdgcn_s_setprio(0);
            *(rb ? hw0 : hw1) = (__bf16)h0;    // write NEXT buffer
            out[oidx] = h0;                    // fire-and-forget (drain shadow)
            oidx += D * N;
            asm volatile("s_waitcnt lgkmcnt(0)" ::: "memory");
            __builtin_amdgcn_s_barrier();
        }
    }

    // h_T (B,D,N) then c_T (B,D,N), appended after outputs.
    const size_t baseH = (size_t)B * T * D * N;
    const size_t baseC = baseH + (size_t)B * D * N;
    const size_t i0 = ((size_t)gb * D + d) * N + mcol;
    out[baseH + i0] = h0;
    out[baseC + i0] = c0;
}

extern "C" void kernel_launch(void* const* d_in, const int* in_sizes, int n_in,
                              void* d_out, int out_size, void* d_ws, size_t ws_size,
                              hipStream_t stream) {
    lstm_kernel<<<dim3(512), dim3(256), 0, stream>>>(
        (const float*)d_in[0],
        (const float*)d_in[1], (const float*)d_in[2],
        (const float*)d_in[3], (const float*)d_in[4],
        (const float*)d_in[5], (const float*)d_in[6],
        (const float*)d_in[7], (const float*)d_in[8],
        (const float*)d_in[9], (const float*)d_in[10],
        (const float*)d_in[11], (const float*)d_in[12],
        (float*)d_out);
}

// Round 4
// 80.552 us; speedup vs baseline: 1.2189x; 1.0020x over previous
//
#include <hip/hip_runtime.h>
#include <hip/hip_bf16.h>
#include <stdint.h>

// LSTMCell: B=64, T=256, D=32, N=64.
// gate[b,d,m] = sum_n h[b,d,n]*W[d,n,m] + x[b,t,d]*U[d,m] + bias[d,m]
//
// Topology (R4/R9, proven 80.2-80.7us): 512 blocks = 32d x 16 batch-tiles
// of 4, 4 waves/block, 2048 waves = 2 blocks/CU, 2 waves/SIMD from
// DIFFERENT blocks. Batches at MFMA rows {0,4,8,12}: each lane owns 1
// element (batch g, col mcol) in acc reg 0; junk A rows (quad-broadcast)
// feed only never-read C regs 1..3.
//
// R15 = R11 minus stagger machinery, plus MERGED-RCP activation algebra.
// History: R10/R11 (blockIdx-hash stagger) null; R14 (physical HW_ID
// slot-parity stagger) null -> anti-phase is dynamically UNSTABLE: the
// co-resident pair is a coupled-oscillator system whose attractor is
// in-phase lock (leader runs against partner's idle phase, speeds up,
// re-locks). No initial offset can hold; sustained forcing only relabels
// the loop point. Anti-phase program abandoned.
// Accounting per SIMD-step (754 cy): VALU 347 + MFMA 222 + idle 185,
// additive under in-phase lock. Only VALU is reducible: 10 trans ops
// (5 exp2 + 5 rcp, ~8cy each wave64) dominate it. Merged-rcp algebra
// cuts 10 -> 8 with identical math:
//   i*j = (Ej-1)/[(Ej+1)(1+Ei)]   (1 rcp, was 2)
//   h   = (Ec-1)/[(Ec+1)(1+Eo)]   (1 rcp, was 2)
//   c   = c*rcp(1+Ef) + i*j       (f's rcp kept)
// No overflow path: |gate| <~ 1.6 (W,U,b ~ 0.02, |h|<=1) -> E <= e^3.2.
//
// R12 lesson: 1 block/CU with 2-elem in-step ILP = 1088 cy/step -> the
// chain is only hideable ACROSS blocks. R13 lesson: zero-C split MFMAs
// lengthen the readout chain; chained-C MFMA with VALU seed is faster.
//
// MFMA k-placement: logical k=8g+j in slot (g,j) for BOTH A and B -> exact
// dot product under any HW slot->k bijection. C/D layout (HW-verified):
// col=lane&15, row=4*(lane>>4)+reg.
//
// Barrier: lgkmcnt-only drain + raw s_barrier (NOT __syncthreads: vmcnt(0)
// would pull the fire-and-forget global h stores into the critical path).
// setprio head/tail kept (R9: +2%).

typedef __attribute__((ext_vector_type(8))) __bf16 bf16x8;
typedef __attribute__((ext_vector_type(4))) float f32x4;

union FragU { uint4 u; bf16x8 v; };

__global__ __launch_bounds__(256, 2) void lstm_kernel(
    const float* __restrict__ x,
    const float* __restrict__ Wj, const float* __restrict__ Wi,
    const float* __restrict__ Wf, const float* __restrict__ Wo,
    const float* __restrict__ Uj, const float* __restrict__ Ui,
    const float* __restrict__ Uf, const float* __restrict__ Uo,
    const float* __restrict__ bj, const float* __restrict__ bi,
    const float* __restrict__ bf, const float* __restrict__ bo,
    float* __restrict__ out)
{
    constexpr int T = 256, D = 32, N = 64, B = 64;
    const int bid   = blockIdx.x;     // 0..511
    const int d     = bid >> 4;       // 0..31
    const int btile = bid & 15;       // 0..15 (4 batches each)
    const int tid   = threadIdx.x;
    const int w     = tid >> 6;       // wave 0..3
    const int lane  = tid & 63;
    const int g     = lane >> 4;      // lane group 0..3
    const int li    = lane & 15;
    const int mcol  = w * 16 + li;    // output feature owned by this lane

    // Compact h exchange: [buf][batch r][64 cols, 16B-chunk-swizzled
    // p = (chunk + 2r) & 7].
    __shared__ __align__(16) __bf16 hbuf[2][4][64];
    __shared__ float xs[4][256];      // x[batch][t] for this (d, btile)

    for (int idx = tid; idx < 2 * 4 * 64; idx += 256)
        (&hbuf[0][0][0])[idx] = (__bf16)0.0f;          // h0 = 0
    for (int idx = tid; idx < 4 * 256; idx += 256) {
        int bl = idx >> 8, t = idx & 255;
        xs[bl][t] = x[((size_t)(btile * 4 + bl) * T + t) * D + d];
    }

    // Persistent per-lane operands: W B-fragments (32 VGPR), U, bias.
    const float* Wg[4] = { Wj, Wi, Wf, Wo };
    const float* Ug[4] = { Uj, Ui, Uf, Uo };
    const float* Bg[4] = { bj, bi, bf, bo };
    FragU wfrag[4][2];
    float uv[4], bv[4];
    #pragma unroll
    for (int G = 0; G < 4; ++G) {
        uv[G] = Ug[G][d * N + mcol];
        bv[G] = Bg[G][d * N + mcol];
        const float* base = Wg[G] + (size_t)d * N * N + mcol;
        #pragma unroll
        for (int f = 0; f < 2; ++f) {
            const int k0 = f * 32 + g * 8;
            bf16x8 tmp;
            #pragma unroll
            for (int j = 0; j < 8; ++j)
                tmp[j] = (__bf16)base[(size_t)(k0 + j) * N];  // W[d][k][m]
            wfrag[G][f].v = tmp;
        }
    }

    f32x4 acc[4];
    #pragma unroll
    for (int G = 0; G < 4; ++G)
        acc[G] = f32x4{ bv[G], bv[G], bv[G], bv[G] };

    // Writer: lane owns (batch g, col mcol) -> row g, swizzled chunk.
    const int cm = mcol >> 3;
    const int woff = (((cm + 2 * g) & 7) << 3) | (mcol & 7);
    __bf16* hw0 = &hbuf[0][g][0] + woff;
    __bf16* hw1 = &hbuf[1][g][0] + woff;

    // Reader (ALL lanes; quads broadcast their leader's address).
    const int rr = li >> 2;                   // A row quad -> batch rr
    const int p0 = (g + 2 * rr) & 7;          // logical chunk g
    const int p1 = (g + 4 + 2 * rr) & 7;      // logical chunk g+4
    const uint4* ra00 = (const uint4*)&hbuf[0][rr][p0 << 3];
    const uint4* ra01 = (const uint4*)&hbuf[1][rr][p0 << 3];
    const uint4* ra10 = (const uint4*)&hbuf[0][rr][p1 << 3];
    const uint4* ra11 = (const uint4*)&hbuf[1][rr][p1 << 3];

    __syncthreads();

    float c0 = 0.f, h0 = 0.f;
    const int gb = btile * 4 + g;     // global batch
    uint32_t oidx = (uint32_t)gb * (T * D * N) + (uint32_t)(d * N + mcol);

    // exp(x) = exp2(K*x); exp(2x) = exp2(K2*x).
    constexpr float K  = 1.4426950408889634f;
    constexpr float K2 = 2.8853900817779268f;

    #pragma unroll 1
    for (int t = 0; t < T; t += 8) {
        const float4 xa = *(const float4*)&xs[g][t];
        const float4 xb = *(const float4*)&xs[g][t + 4];
        #pragma unroll
        for (int uu = 0; uu < 8; ++uu) {
            // CHAIN HEAD at high priority (R9 +2%).
            __builtin_amdgcn_s_setprio(1);
            const int rb = uu & 1;             // read buffer = tt&1
            FragU a0, a1;
            a0.u = *(rb ? ra01 : ra00);
            a1.u = *(rb ? ra11 : ra10);
            const float xv = (uu < 4) ? xa[uu] : xb[uu - 4];
            #pragma unroll
            for (int G = 0; G < 4; ++G)
                acc[G][0] = __builtin_fmaf(xv, uv[G], bv[G]);
            #pragma unroll
            for (int G = 0; G < 4; ++G) {
                acc[G] = __builtin_amdgcn_mfma_f32_16x16x32_bf16(a0.v, wfrag[G][0].v, acc[G], 0, 0, 0);
                acc[G] = __builtin_amdgcn_mfma_f32_16x16x32_bf16(a1.v, wfrag[G][1].v, acc[G], 0, 0, 0);
            }
            // Merged-rcp activations (8 trans, was 10). Exact algebra:
            //   j = tanh(gj) = (Ej-1)/(Ej+1),  Ej = exp(2*gj)
            //   i = 1/(1+Ei), Ei = exp(-gi);  f,o likewise
            //   i*j = (Ej-1)/[(Ej+1)(1+Ei)]
            //   c'  = c*rcp(1+Ef) + i*j
            //   h   = o*tanh(c') = (Ec-1)/[(Ec+1)(1+Eo)], Ec = exp(2*c')
            const float Ej = __builtin_amdgcn_exp2f( K2 * acc[0][0]);
            const float Ei = __builtin_amdgcn_exp2f(-K  * acc[1][0]);
            const float Ef = __builtin_amdgcn_exp2f(-K  * acc[2][0]);
            const float Eo = __builtin_amdgcn_exp2f(-K  * acc[3][0]);
            const float Rij = __builtin_amdgcn_rcpf((Ej + 1.0f) * (1.0f + Ei));
            const float ij  = (Ej - 1.0f) * Rij;
            const float Rf  = __builtin_amdgcn_rcpf(1.0f + Ef);
            c0 = __builtin_fmaf(c0, Rf, ij);
            const float Ec = __builtin_amdgcn_exp2f(K2 * c0);
            const float Rh = __builtin_amdgcn_rcpf((Ec + 1.0f) * (1.0f + Eo));
            h0 = (Ec - 1.0f) * Rh;
            // TAIL at low priority.
            __builtin_amdgcn_s_setprio(0);
            *(rb ? hw0 : hw1) = (__bf16)h0;    // write NEXT buffer
            out[oidx] = h0;                    // fire-and-forget (drain shadow)
            oidx += D * N;
            asm volatile("s_waitcnt lgkmcnt(0)" ::: "memory");
            __builtin_amdgcn_s_barrier();
        }
    }

    // h_T (B,D,N) then c_T (B,D,N), appended after outputs.
    const size_t baseH = (size_t)B * T * D * N;
    const size_t baseC = baseH + (size_t)B * D * N;
    const size_t i0 = ((size_t)gb * D + d) * N + mcol;
    out[baseH + i0] = h0;
    out[baseC + i0] = c0;
}

extern "C" void kernel_launch(void* const* d_in, const int* in_sizes, int n_in,
                              void* d_out, int out_size, void* d_ws, size_t ws_size,
                              hipStream_t stream) {
    lstm_kernel<<<dim3(512), dim3(256), 0, stream>>>(
        (const float*)d_in[0],
        (const float*)d_in[1], (const float*)d_in[2],
        (const float*)d_in[3], (const float*)d_in[4],
        (const float*)d_in[5], (const float*)d_in[6],
        (const float*)d_in[7], (const float*)d_in[8],
        (const float*)d_in[9], (const float*)d_in[10],
        (const float*)d_in[11], (const float*)d_in[12],
        (float*)d_out);
}